// Round 21
// baseline (1147.929 us; speedup 1.0000x reference)
//
#include <hip/hip_runtime.h>
#include <math.h>
#include <stdint.h>

#define DM    1024
#define NH    16
#define DH    64
#define NL    6
#define DFF   4096
#define QLEN  512
#define MLEN  128
#define B_    4
#define KL    640
#define CLAMP 512
#define EPS   1e-5f

typedef _Float16 f16x8 __attribute__((ext_vector_type(8)));
typedef _Float16 f16x4 __attribute__((ext_vector_type(4)));
typedef float    f32x4 __attribute__((ext_vector_type(4)));

// ---- async global->LDS, 16B per lane; LDS base must be wave-uniform ----
__device__ __forceinline__ void gload16(const void* g, void* l) {
  __builtin_amdgcn_global_load_lds(
      (const __attribute__((address_space(1))) void*)g,
      (__attribute__((address_space(3))) void*)l, 16, 0, 0);
}

// ---------------- block-wide sum over 256 threads (4 waves) ----------------
__device__ __forceinline__ float block_sum(float v, float* sm4) {
#pragma unroll
  for (int o = 32; o > 0; o >>= 1) v += __shfl_down(v, o, 64);
  int lane = threadIdx.x & 63, wid = threadIdx.x >> 6;
  if (lane == 0) sm4[wid] = v;
  __syncthreads();
  float r = sm4[0] + sm4[1] + sm4[2] + sm4[3];
  __syncthreads();
  return r;
}

// ---------------- sinusoidal relative position embedding (f16 out) ----------------
__global__ __launch_bounds__(256) void pos_emb_kernel(_Float16* __restrict__ pe) {
  int p = blockIdx.x;                       // 0..KL-1
  float pos = fminf((float)(KL - 1 - p), (float)CLAMP);
  for (int f = threadIdx.x; f < 512; f += 256) {
    float inv = powf(10000.0f, -(float)f * (1.0f / 512.0f));
    float a = pos * inv;
    pe[(size_t)p * DM + f]       = (_Float16)sinf(a);
    pe[(size_t)p * DM + 512 + f] = (_Float16)cosf(a);
  }
}

// ---------------- cast ALL layers' weights fp32 -> f16, nontemporal ----------------
// Streamed-once data: nt loads/stores bypass L2/L3 (no cache thrash).
// Uses clang ext_vector types (native vectors) - HIP float4 class is rejected
// by __builtin_nontemporal_*.
__global__ __launch_bounds__(256) void cast_all_kernel(
    const float* __restrict__ qkv, const float* __restrict__ rw,
    const float* __restrict__ ow, const float* __restrict__ f1,
    const float* __restrict__ f2,
    _Float16* __restrict__ dq, _Float16* __restrict__ dr,
    _Float16* __restrict__ dow, _Float16* __restrict__ d1,
    _Float16* __restrict__ d2) {
  size_t i = (size_t)blockIdx.x * 4096;
  const float* s; _Float16* d; size_t off;
  if (i < 18874368)      { s = qkv; d = dq;  off = 0; }
  else if (i < 25165824) { s = rw;  d = dr;  off = 18874368; }
  else if (i < 31457280) { s = ow;  d = dow; off = 25165824; }
  else if (i < 56623104) { s = f1;  d = d1;  off = 31457280; }
  else                   { s = f2;  d = d2;  off = 56623104; }
  size_t kb = i - off + threadIdx.x * 8;
#pragma unroll
  for (int e = 0; e < 2; ++e) {
    size_t k = kb + e * 2048;
    f32x4 a = __builtin_nontemporal_load((const f32x4*)(s + k));
    f32x4 b = __builtin_nontemporal_load((const f32x4*)(s + k + 4));
    f16x8 o = { (_Float16)a.x, (_Float16)a.y, (_Float16)a.z, (_Float16)a.w,
                (_Float16)b.x, (_Float16)b.y, (_Float16)b.z, (_Float16)b.w };
    __builtin_nontemporal_store(o, (f16x8*)(d + k));
  }
}

// ---------------- LayerNorm over D=1024; optional 2-source concat ----------------
template <int OUTF16>
__global__ __launch_bounds__(256) void ln_kernel(
    const float* __restrict__ src0, const float* __restrict__ src1,
    const float* __restrict__ g, const float* __restrict__ b,
    float* __restrict__ outf, _Float16* __restrict__ outh, int rows0) {
  __shared__ float sm4[4];
  int row = blockIdx.x;
  const float* src = (row < rows0) ? (src0 + (size_t)row * DM)
                                   : (src1 + (size_t)(row - rows0) * DM);
  float4 v = ((const float4*)src)[threadIdx.x];
  float mean = block_sum(v.x + v.y + v.z + v.w, sm4) * (1.0f / DM);
  float dx = v.x - mean, dy = v.y - mean, dz = v.z - mean, dw = v.w - mean;
  float var = block_sum(dx * dx + dy * dy + dz * dz + dw * dw, sm4) * (1.0f / DM);
  float rstd = rsqrtf(var + EPS);
  float4 gg = ((const float4*)g)[threadIdx.x];
  float4 bb = ((const float4*)b)[threadIdx.x];
  float ox = dx * rstd * gg.x + bb.x;
  float oy = dy * rstd * gg.y + bb.y;
  float oz = dz * rstd * gg.z + bb.z;
  float ow = dw * rstd * gg.w + bb.w;
  if (OUTF16) {
    f16x4 o = { (_Float16)ox, (_Float16)oy, (_Float16)oz, (_Float16)ow };
    *(f16x4*)(outh + (size_t)row * DM + threadIdx.x * 4) = o;
  } else {
    float4 o = { ox, oy, oz, ow };
    ((float4*)(outf + (size_t)row * DM))[threadIdx.x] = o;
  }
}

// ------- fused split-K reduce + residual (+bias) + LayerNorm, one block/row -------
template <int SK, int BIAS, int OUTF16>
__global__ __launch_bounds__(256) void reduce_ln_kernel(
    const _Float16* __restrict__ pk, const float* __restrict__ bias,
    const float* __restrict__ resid, const float* __restrict__ g,
    const float* __restrict__ b, float* __restrict__ xout,
    _Float16* __restrict__ houth, float* __restrict__ houtf, int MN) {
  __shared__ float sm4[4];
  const int row = blockIdx.x;
  const int c = threadIdx.x * 4;
  const size_t base = (size_t)row * DM + c;
  float s[4] = {};
#pragma unroll
  for (int z = 0; z < SK; ++z) {
    f16x4 v = *(const f16x4*)(pk + (size_t)z * MN + base);
#pragma unroll
    for (int e = 0; e < 4; ++e) s[e] += (float)v[e];
  }
  if (BIAS) {
    float4 bv = *(const float4*)(bias + c);
    s[0] += bv.x; s[1] += bv.y; s[2] += bv.z; s[3] += bv.w;
  }
  float4 rv = *(const float4*)(resid + base);
  s[0] += rv.x; s[1] += rv.y; s[2] += rv.z; s[3] += rv.w;
  float4 xo = { s[0], s[1], s[2], s[3] };
  *(float4*)(xout + base) = xo;
  float mean = block_sum(s[0] + s[1] + s[2] + s[3], sm4) * (1.0f / DM);
  float d0 = s[0] - mean, d1 = s[1] - mean, d2 = s[2] - mean, d3 = s[3] - mean;
  float var = block_sum(d0 * d0 + d1 * d1 + d2 * d2 + d3 * d3, sm4) * (1.0f / DM);
  float rstd = rsqrtf(var + EPS);
  float4 gg = *(const float4*)(g + c);
  float4 bb = *(const float4*)(b + c);
  float o0 = d0 * rstd * gg.x + bb.x, o1 = d1 * rstd * gg.y + bb.y;
  float o2 = d2 * rstd * gg.z + bb.z, o3 = d3 * rstd * gg.w + bb.w;
  if (OUTF16) {
    f16x4 oh = { (_Float16)o0, (_Float16)o1, (_Float16)o2, (_Float16)o3 };
    *(f16x4*)(houth + base) = oh;
  } else {
    float4 of = { o0, o1, o2, o3 };
    *(float4*)(houtf + base) = of;
  }
}

// ---------------- f16 MFMA GEMM, BK=64, XOR-swizzled LDS ----------------
template <int BIAS, int RELU, int RESID, int OUTF16>
__global__ __launch_bounds__(256) void gemm_mfma(
    const _Float16* __restrict__ A, const _Float16* __restrict__ B,
    const float* __restrict__ bias, const float* __restrict__ resid,
    float* __restrict__ Cf, _Float16* __restrict__ Ch,
    int M, int N, int K) {
  __shared__ alignas(16) _Float16 As[128 * 64];
  __shared__ alignas(16) _Float16 Bs[128 * 64];
  const int t = threadIdx.x;
  const int lane = t & 63, wid = t >> 6;
  const int li = lane & 15, g = lane >> 4;
  const int m0 = blockIdx.y * 128, n0 = blockIdx.x * 128;
  const int wm = (wid >> 1) * 64, wn = (wid & 1) * 64;

  const _Float16* Ap[4];
  const _Float16* Bp[4];
  _Float16 *Asw[4], *Bsw[4];
#pragma unroll
  for (int it = 0; it < 4; ++it) {
    int c = it * 256 + wid * 64 + lane;
    int rr = c >> 3, gk = ((c & 7) ^ (rr & 7)) * 8;
    Ap[it] = A + (size_t)(m0 + rr) * K + gk;
    Bp[it] = B + (size_t)(n0 + rr) * K + gk;
    Asw[it] = &As[(it * 256 + wid * 64) * 8];
    Bsw[it] = &Bs[(it * 256 + wid * 64) * 8];
  }

  f32x4 acc[4][4] = {};
  for (int k0 = 0; k0 < K; k0 += 64) {
    __syncthreads();
#pragma unroll
    for (int it = 0; it < 4; ++it) gload16(Ap[it] + k0, Asw[it]);
#pragma unroll
    for (int it = 0; it < 4; ++it) gload16(Bp[it] + k0, Bsw[it]);
    __syncthreads();
#pragma unroll
    for (int kh = 0; kh < 2; ++kh) {
      f16x8 af[4], bf[4];
      const int sl = ((kh * 4 + g) ^ (li & 7)) * 8;
#pragma unroll
      for (int f = 0; f < 4; ++f) {
        af[f] = *(const f16x8*)&As[(wm + f * 16 + li) * 64 + sl];
        bf[f] = *(const f16x8*)&Bs[(wn + f * 16 + li) * 64 + sl];
      }
#pragma unroll
      for (int i = 0; i < 4; ++i)
#pragma unroll
        for (int j = 0; j < 4; ++j)
          acc[i][j] = __builtin_amdgcn_mfma_f32_16x16x32_f16(af[i], bf[j], acc[i][j], 0, 0, 0);
    }
  }
#pragma unroll
  for (int i = 0; i < 4; ++i) {
#pragma unroll
    for (int j = 0; j < 4; ++j) {
      const int n = n0 + wn + j * 16 + li;
      float bv = 0.0f;
      if (BIAS) bv = bias[n];
#pragma unroll
      for (int r = 0; r < 4; ++r) {
        const int m = m0 + wm + i * 16 + g * 4 + r;
        float v = acc[i][j][r] + bv;
        if (RELU) v = fmaxf(v, 0.0f);
        if (RESID) v += resid[(size_t)m * N + n];
        if (OUTF16) Ch[(size_t)m * N + n] = (_Float16)v;
        else        Cf[(size_t)m * N + n] = v;
      }
    }
  }
}

// ---------------- split-K GEMM, BK=64, XOR-swizzled (Ks multiple of 64) ----------------
__global__ __launch_bounds__(256) void gemm_sk(
    const _Float16* __restrict__ A, const _Float16* __restrict__ B,
    _Float16* __restrict__ pk, int M, int N, int K, int Ks) {
  __shared__ alignas(16) _Float16 As[128 * 64];
  __shared__ alignas(16) _Float16 Bs[128 * 64];
  const int t = threadIdx.x;
  const int lane = t & 63, wid = t >> 6;
  const int li = lane & 15, g = lane >> 4;
  const int m0 = blockIdx.y * 128, n0 = blockIdx.x * 128;
  const int z = blockIdx.z;
  const int kbase = z * Ks;
  const int wm = (wid >> 1) * 64, wn = (wid & 1) * 64;

  const _Float16* Ap[4];
  const _Float16* Bp[4];
  _Float16 *Asw[4], *Bsw[4];
#pragma unroll
  for (int it = 0; it < 4; ++it) {
    int c = it * 256 + wid * 64 + lane;
    int rr = c >> 3, gk = ((c & 7) ^ (rr & 7)) * 8;
    Ap[it] = A + (size_t)(m0 + rr) * K + kbase + gk;
    Bp[it] = B + (size_t)(n0 + rr) * K + kbase + gk;
    Asw[it] = &As[(it * 256 + wid * 64) * 8];
    Bsw[it] = &Bs[(it * 256 + wid * 64) * 8];
  }

  f32x4 acc[4][4] = {};
  for (int k0 = 0; k0 < Ks; k0 += 64) {
    __syncthreads();
#pragma unroll
    for (int it = 0; it < 4; ++it) gload16(Ap[it] + k0, Asw[it]);
#pragma unroll
    for (int it = 0; it < 4; ++it) gload16(Bp[it] + k0, Bsw[it]);
    __syncthreads();
#pragma unroll
    for (int kh = 0; kh < 2; ++kh) {
      f16x8 af[4], bf[4];
      const int sl = ((kh * 4 + g) ^ (li & 7)) * 8;
#pragma unroll
      for (int f = 0; f < 4; ++f) {
        af[f] = *(const f16x8*)&As[(wm + f * 16 + li) * 64 + sl];
        bf[f] = *(const f16x8*)&Bs[(wn + f * 16 + li) * 64 + sl];
      }
#pragma unroll
      for (int i = 0; i < 4; ++i)
#pragma unroll
        for (int j = 0; j < 4; ++j)
          acc[i][j] = __builtin_amdgcn_mfma_f32_16x16x32_f16(af[i], bf[j], acc[i][j], 0, 0, 0);
    }
  }
  _Float16* out = pk + (size_t)z * M * N;
#pragma unroll
  for (int i = 0; i < 4; ++i)
#pragma unroll
    for (int j = 0; j < 4; ++j) {
      const int n = n0 + wn + j * 16 + li;
#pragma unroll
      for (int r = 0; r < 4; ++r) {
        const int m = m0 + wm + i * 16 + g * 4 + r;
        out[(size_t)m * N + n] = (_Float16)acc[i][j][r];
      }
    }
}

// ---------------- split-K reduce (no LN): C = sum_z pk[z] ----------------
template <int SK, int OUTF16>
__global__ __launch_bounds__(256) void reduce_k(
    const _Float16* __restrict__ pk, float* __restrict__ Cf,
    _Float16* __restrict__ Ch, int MN) {
  const int idx = (blockIdx.x * 256 + threadIdx.x) * 8;
  float s[8] = {};
#pragma unroll
  for (int zz = 0; zz < SK; ++zz) {
    f16x8 v = *(const f16x8*)(pk + (size_t)zz * MN + idx);
#pragma unroll
    for (int e = 0; e < 8; ++e) s[e] += (float)v[e];
  }
  if (OUTF16) {
    f16x8 o;
#pragma unroll
    for (int e = 0; e < 8; ++e) o[e] = (_Float16)s[e];
    *(f16x8*)(Ch + idx) = o;
  } else {
    float4 o0 = { s[0], s[1], s[2], s[3] };
    float4 o1 = { s[4], s[5], s[6], s[7] };
    *(float4*)(Cf + idx) = o0;
    *(float4*)(Cf + idx + 4) = o1;
  }
}

// ---------------- MFMA flash relative attention, KV-split x8 ----------------
// grid (8 q-tiles, 16 heads, 32 = batch + 4*z); 256 threads = 4 waves x 16 q-rows.
// Block zz handles key-tiles tt = zz, zz+8, ... (max 2). Empty blocks write
// zero-mass partials; the renormalizing combine handles them exactly.
__global__ __launch_bounds__(256, 3) void attn_kernel(
    const _Float16* __restrict__ wh,  // (KL*B_, 3072) f16 qkv projections
    const _Float16* __restrict__ rk,  // rk_all + l*1024, row stride 6144
    const float* __restrict__ rwb,    // (16,64)
    const float* __restrict__ rrb,    // (16,64)
    _Float16* __restrict__ po,        // [8][QLEN*B_*1024] partial O-hat
    float* __restrict__ pm,           // [8][32768] running max (log2 domain)
    float* __restrict__ pl) {         // [8][32768] running sum
  __shared__ alignas(16) _Float16 KS[64 * 72];   // K tile
  __shared__ alignas(16) _Float16 VT[64 * 72];   // V^T tile [d][j]
  __shared__ alignas(16) _Float16 RR[128 * 72];  // R tile
  __shared__ alignas(16) _Float16 QS[4][16 * 72];  // per-wave: shifted QR, then P

  const int i0 = blockIdx.x * 64, n = blockIdx.y;
  const int b = blockIdx.z & 3, zz = blockIdx.z >> 2;
  const int t = threadIdx.x, lane = t & 63, wid = t >> 6;
  const int g = lane >> 4, li = lane & 15;
  const int strip = wid * 16;
  _Float16* QSw = QS[wid];

  f16x8 qw[2], qr[2];
#pragma unroll
  for (int ks_ = 0; ks_ < 2; ++ks_) {
    const _Float16* qp =
        wh + ((size_t)(MLEN + i0 + strip + li) * B_ + b) * 3072 + n * 64 + ks_ * 32 + g * 8;
    f16x8 qv = *(const f16x8*)qp;
#pragma unroll
    for (int e = 0; e < 8; ++e) {
      float f0 = (float)qv[e];
      qw[ks_][e] = (_Float16)(f0 + rwb[n * 64 + ks_ * 32 + g * 8 + e]);
      qr[ks_][e] = (_Float16)(f0 + rrb[n * 64 + ks_ * 32 + g * 8 + e]);
    }
  }

  f32x4 o_[4] = {};
  float mrun[4], lrun[4];
#pragma unroll
  for (int r = 0; r < 4; ++r) { mrun[r] = -INFINITY; lrun[r] = 0.0f; }

  const float SC = 0.125f * 1.44269504f;  // scale * log2(e): softmax in base 2
  const int ntiles = i0 / 64 + 3;
  for (int tt = zz; tt < ntiles; tt += 8) {
    const int j0 = tt * 64;
    __syncthreads();  // prev-tile reads of KS/VT/RR done
    {
      int row = t >> 2, c = (t & 3) * 16;
      const _Float16* kp = wh + ((size_t)(j0 + row) * B_ + b) * 3072 + 1024 + n * 64 + c;
      *(f16x8*)&KS[row * 72 + c] = *(const f16x8*)kp;
      *(f16x8*)&KS[row * 72 + c + 8] = *(const f16x8*)(kp + 8);
    }
#pragma unroll
    for (int it = 0; it < 2; ++it) {
      int j = t & 63, d0 = (t >> 6) * 8 + it * 32;
      f16x8 vv = *(const f16x8*)(wh + ((size_t)(j0 + j) * B_ + b) * 3072 + 2048 + n * 64 + d0);
#pragma unroll
      for (int e = 0; e < 8; ++e) VT[(d0 + e) * 72 + j] = vv[e];
    }
    {
      int row = t >> 1, c = (t & 1) * 32;
      int mrow = j0 - i0 + 448 + row;
      if (mrow > KL - 1) mrow = KL - 1;
      const _Float16* rp = rk + (size_t)mrow * 6144 + n * 64 + c;
#pragma unroll
      for (int cc = 0; cc < 32; cc += 8)
        *(f16x8*)&RR[row * 72 + c + cc] = *(const f16x8*)(rp + cc);
    }
    __syncthreads();
    // ---- QK^T: 4 col-frags ----
    f32x4 acs[4] = {};
#pragma unroll
    for (int ks_ = 0; ks_ < 2; ++ks_)
#pragma unroll
      for (int cf = 0; cf < 4; ++cf) {
        f16x8 bk = *(const f16x8*)&KS[(cf * 16 + li) * 72 + ks_ * 32 + g * 8];
        acs[cf] = __builtin_amdgcn_mfma_f32_16x16x32_f16(qw[ks_], bk, acs[cf], 0, 0, 0);
      }
    // ---- QR; shifted store QSw[il_loc][jl] = QR[il][jl-il+63] (wave-private) ----
#pragma unroll
    for (int half = 0; half < 2; ++half) {
      f32x4 acq[4] = {};
#pragma unroll
      for (int ks_ = 0; ks_ < 2; ++ks_)
#pragma unroll
        for (int cf = 0; cf < 4; ++cf) {
          f16x8 br = *(const f16x8*)&RR[((half * 4 + cf) * 16 + li) * 72 + ks_ * 32 + g * 8];
          acq[cf] = __builtin_amdgcn_mfma_f32_16x16x32_f16(qr[ks_], br, acq[cf], 0, 0, 0);
        }
#pragma unroll
      for (int cf = 0; cf < 4; ++cf)
#pragma unroll
        for (int r = 0; r < 4; ++r) {
          int il = strip + g * 4 + r;
          int jl = (half * 4 + cf) * 16 + li - 63 + il;
          if ((unsigned)jl < 64u) QSw[(g * 4 + r) * 72 + jl] = (_Float16)acq[cf][r];
        }
    }
    // ---- online softmax (log2 domain) — wave-private, no barrier ----
    float pf[4][4], fac[4];
#pragma unroll
    for (int r = 0; r < 4; ++r) {
      int il = strip + g * 4 + r, gi = i0 + il;
      float sv[4], mx = -INFINITY;
#pragma unroll
      for (int cf = 0; cf < 4; ++cf) {
        int jl = cf * 16 + li;
        float v = (acs[cf][r] + (float)QSw[(g * 4 + r) * 72 + jl]) * SC;
        if (j0 + jl > gi + MLEN) v = -INFINITY;
        sv[cf] = v;
        mx = fmaxf(mx, v);
      }
#pragma unroll
      for (int o2 = 1; o2 < 16; o2 <<= 1) mx = fmaxf(mx, __shfl_xor(mx, o2, 64));
      float mnew = fmaxf(mrun[r], mx);
      float fc = exp2f(mrun[r] - mnew);
      float sum = 0.0f;
#pragma unroll
      for (int cf = 0; cf < 4; ++cf) { pf[cf][r] = exp2f(sv[cf] - mnew); sum += pf[cf][r]; }
#pragma unroll
      for (int o2 = 1; o2 < 16; o2 <<= 1) sum += __shfl_xor(sum, o2, 64);
      lrun[r] = lrun[r] * fc + sum;
      mrun[r] = mnew;
      fac[r] = fc;
    }
    // ---- P -> QSw (wave-private overwrite, in-order DS) ----
#pragma unroll
    for (int cf = 0; cf < 4; ++cf)
#pragma unroll
      for (int r = 0; r < 4; ++r)
        QSw[(g * 4 + r) * 72 + cf * 16 + li] = (_Float16)pf[cf][r];
    // ---- PV: O = O*fac + P V ----
#pragma unroll
    for (int cf = 0; cf < 4; ++cf)
#pragma unroll
      for (int r = 0; r < 4; ++r)
        o_[cf][r] *= fac[r];
#pragma unroll
    for (int ks_ = 0; ks_ < 2; ++ks_) {
      f16x8 pa = *(const f16x8*)&QSw[li * 72 + ks_ * 32 + g * 8];
#pragma unroll
      for (int cf = 0; cf < 4; ++cf) {
        f16x8 bv = *(const f16x8*)&VT[(cf * 16 + li) * 72 + ks_ * 32 + g * 8];
        o_[cf] = __builtin_amdgcn_mfma_f32_16x16x32_f16(pa, bv, o_[cf], 0, 0, 0);
      }
    }
  }
  const size_t obase = (size_t)zz * (QLEN * B_ * 1024);
#pragma unroll
  for (int cf = 0; cf < 4; ++cf)
#pragma unroll
    for (int r = 0; r < 4; ++r) {
      int row = strip + g * 4 + r;
      float l = lrun[r];
      float oo = (l > 0.0f) ? o_[cf][r] / l : 0.0f;
      po[obase + ((size_t)(i0 + row) * B_ + b) * 1024 + n * 64 + cf * 16 + li] = (_Float16)oo;
    }
  if (li == 0) {
#pragma unroll
    for (int r = 0; r < 4; ++r) {
      int row = strip + g * 4 + r;
      int idx = ((i0 + row) * B_ + b) * 16 + n;
      pm[zz * 32768 + idx] = (lrun[r] > 0.0f) ? mrun[r] : -3.0e38f;
      pl[zz * 32768 + idx] = lrun[r];
    }
  }
}

// ---------------- combine the eight KV-split slices ----------------
__global__ __launch_bounds__(256) void attn_combine(
    const _Float16* __restrict__ po, const float* __restrict__ pm,
    const float* __restrict__ pl, _Float16* __restrict__ av) {
  const size_t e = ((size_t)blockIdx.x * 256 + threadIdx.x) * 8;
  const int mlidx = (int)(e >> 10) * 16 + (((int)e & 1023) >> 6);
  float m[8], l[8];
#pragma unroll
  for (int z = 0; z < 8; ++z) { m[z] = pm[z * 32768 + mlidx]; l[z] = pl[z * 32768 + mlidx]; }
  float M = m[0];
#pragma unroll
  for (int z = 1; z < 8; ++z) M = fmaxf(M, m[z]);
  float w[8], wsum = 0.0f;
#pragma unroll
  for (int z = 0; z < 8; ++z) { w[z] = l[z] * exp2f(m[z] - M); wsum += w[z]; }
  float inv = 1.0f / wsum;
  float s[8] = {};
#pragma unroll
  for (int z = 0; z < 8; ++z) {
    f16x8 oz = *(const f16x8*)(po + (size_t)z * 2097152 + e);
    float wz = w[z] * inv;
#pragma unroll
    for (int k = 0; k < 8; ++k) s[k] += wz * (float)oz[k];
  }
  f16x8 o;
#pragma unroll
  for (int k = 0; k < 8; ++k) o[k] = (_Float16)s[k];
  *(f16x8*)(av + e) = o;
}

// ---------------- host ----------------
extern "C" void kernel_launch(void* const* d_in, const int* in_sizes, int n_in,
                              void* d_out, int out_size, void* d_ws, size_t ws_size,
                              hipStream_t stream) {
  const float* inputs = (const float*)d_in[0];
  const float* mems   = (const float*)d_in[1];
  const float* rwb    = (const float*)d_in[2];
  const float* rrb    = (const float*)d_in[3];
  const float* qkv_w  = (const float*)d_in[4];
  const float* r_w    = (const float*)d_in[5];
  const float* o_w    = (const float*)d_in[6];
  const float* ln1_g  = (const float*)d_in[7];
  const float* ln1_b  = (const float*)d_in[8];
  const float* ff_w1  = (const float*)d_in[9];
  const float* ff_b1  = (const float*)d_in[10];
  const float* ff_w2  = (const float*)d_in[11];
  const float* ff_b2  = (const float*)d_in[12];
  const float* ln2_g  = (const float*)d_in[13];
  const float* ln2_b  = (const float*)d_in[14];
  const float* fin_g  = (const float*)d_in[15];
  const float* fin_b  = (const float*)d_in[16];
  float* out = (float*)d_out;

  float* ws = (float*)d_ws;
  float* xbuf = ws;                               // 2,097,152 f32 (8MB)
  _Float16* fb = (_Float16*)(ws + 2097152);
  _Float16* wh_h   = fb;                          //  7,864,320
  _Float16* rk_all = wh_h + 7864320;              //  3,932,160 (640 x 6144, all layers)
  _Float16* pe_h   = rk_all + 3932160;            //    655,360
  _Float16* h_h    = pe_h + 655360;               //  2,621,440
  _Float16* av_h   = h_h + 2621440;               //  2,097,152
  _Float16* ffh_h  = av_h + 2097152;              //  8,388,608
  _Float16* pk     = ffh_h + 8388608;             //  8,388,608 (split-K partials)
  _Float16* po     = pk + 8388608;                // 16,777,216 (attn partial O x8)
  float*    pm     = (float*)(po + 16777216);     //  262,144 f32
  float*    pl     = pm + 262144;                 //  262,144 f32
  _Float16* wq_all = (_Float16*)(pl + 262144);    // 18,874,368
  _Float16* rw_all = wq_all + 18874368;           //  6,291,456
  _Float16* wo_all = rw_all + 6291456;            //  6,291,456
  _Float16* w1_all = wo_all + 6291456;            // 25,165,824
  _Float16* w2_all = w1_all + 25165824;           // 25,165,824  (total ~291MB < 384MB ws)

  // ---- upfront: pos emb, all-layer weight cast, all-layer r_head_k ----
  pos_emb_kernel<<<KL, 256, 0, stream>>>(pe_h);
  cast_all_kernel<<<19968, 256, 0, stream>>>(
      qkv_w, r_w, o_w, ff_w1, ff_w2, wq_all, rw_all, wo_all, w1_all, w2_all);
  gemm_sk<<<dim3(6144 / 128, 640 / 128, 2), 256, 0, stream>>>(
      pe_h, rw_all, pk, KL, 6144, DM, DM / 2);
  reduce_k<2, 1><<<KL * 6144 / 2048, 256, 0, stream>>>(
      pk, nullptr, rk_all, KL * 6144);

  // layer-0 LN1 over [mems_0 ; inputs] -> h_h (2560 rows)
  ln_kernel<1><<<KL * B_, 256, 0, stream>>>(
      mems, inputs, ln1_g, ln1_b, nullptr, h_h, MLEN * B_);

  const float* xcur = inputs;
  for (int l = 0; l < NL; ++l) {
    // QKV projection -> wh f16
    gemm_mfma<0, 0, 0, 1><<<dim3(3072 / 128, 2560 / 128), 256, 0, stream>>>(
        h_h, wq_all + (size_t)l * 3145728, nullptr, nullptr, nullptr, wh_h, 2560, 3072, DM);
    // attention (KV-split x8) -> partials -> combine -> av_h
    attn_kernel<<<dim3(QLEN / 64, NH, B_ * 8), 256, 0, stream>>>(
        wh_h, rk_all + (size_t)l * 1024, rwb, rrb, po, pm, pl);
    attn_combine<<<1024, 256, 0, stream>>>(po, pm, pl, av_h);
    // out projection: split-K=4 (Ks=256) -> fused reduce(+resid)+LN2 -> xbuf, h_h
    gemm_sk<<<dim3(DM / 128, (QLEN * B_) / 128, 4), 256, 0, stream>>>(
        av_h, wo_all + (size_t)l * 1048576, pk, QLEN * B_, DM, DM, DM / 4);
    reduce_ln_kernel<4, 0, 1><<<QLEN * B_, 256, 0, stream>>>(
        pk, nullptr, xcur, ln2_g + l * DM, ln2_b + l * DM, xbuf, h_h, nullptr,
        QLEN * B_ * DM);
    // FFN
    gemm_mfma<1, 1, 0, 1><<<dim3(DFF / 128, (QLEN * B_) / 128), 256, 0, stream>>>(
        h_h, w1_all + (size_t)l * 4194304, ff_b1 + (size_t)l * DFF, nullptr,
        nullptr, ffh_h, QLEN * B_, DFF, DM);
    gemm_sk<<<dim3(DM / 128, (QLEN * B_) / 128, 4), 256, 0, stream>>>(
        ffh_h, w2_all + (size_t)l * 4194304, pk, QLEN * B_, DM, DFF, DFF / 4);
    if (l < NL - 1) {
      reduce_ln_kernel<4, 1, 1><<<QLEN * B_, 256, 0, stream>>>(
          pk, ff_b2 + (size_t)l * DM, xbuf, ln1_g + (size_t)(l + 1) * DM,
          ln1_b + (size_t)(l + 1) * DM, xbuf, h_h + 524288, nullptr,
          QLEN * B_ * DM);
      ln_kernel<1><<<MLEN * B_, 256, 0, stream>>>(
          mems + (size_t)(l + 1) * MLEN * B_ * DM, nullptr,
          ln1_g + (size_t)(l + 1) * DM, ln1_b + (size_t)(l + 1) * DM,
          nullptr, h_h, 1 << 30);
    } else {
      reduce_ln_kernel<4, 1, 0><<<QLEN * B_, 256, 0, stream>>>(
          pk, ff_b2 + (size_t)l * DM, xbuf, fin_g, fin_b, xbuf, nullptr, out,
          QLEN * B_ * DM);
    }
    xcur = xbuf;
  }
}

// Round 22
// 1093.205 us; speedup vs baseline: 1.0501x; 1.0501x over previous
//
#include <hip/hip_runtime.h>
#include <math.h>
#include <stdint.h>

#define DM    1024
#define NH    16
#define DH    64
#define NL    6
#define DFF   4096
#define QLEN  512
#define MLEN  128
#define B_    4
#define KL    640
#define CLAMP 512
#define EPS   1e-5f

typedef _Float16 f16x8 __attribute__((ext_vector_type(8)));
typedef _Float16 f16x4 __attribute__((ext_vector_type(4)));
typedef float    f32x4 __attribute__((ext_vector_type(4)));

// ---- async global->LDS, 16B per lane; LDS base must be wave-uniform ----
__device__ __forceinline__ void gload16(const void* g, void* l) {
  __builtin_amdgcn_global_load_lds(
      (const __attribute__((address_space(1))) void*)g,
      (__attribute__((address_space(3))) void*)l, 16, 0, 0);
}

// ---------------- block-wide sum over 256 threads (4 waves) ----------------
__device__ __forceinline__ float block_sum(float v, float* sm4) {
#pragma unroll
  for (int o = 32; o > 0; o >>= 1) v += __shfl_down(v, o, 64);
  int lane = threadIdx.x & 63, wid = threadIdx.x >> 6;
  if (lane == 0) sm4[wid] = v;
  __syncthreads();
  float r = sm4[0] + sm4[1] + sm4[2] + sm4[3];
  __syncthreads();
  return r;
}

// ---------------- sinusoidal relative position embedding (f16 out) ----------------
__global__ __launch_bounds__(256) void pos_emb_kernel(_Float16* __restrict__ pe) {
  int p = blockIdx.x;                       // 0..KL-1
  float pos = fminf((float)(KL - 1 - p), (float)CLAMP);
  for (int f = threadIdx.x; f < 512; f += 256) {
    float inv = powf(10000.0f, -(float)f * (1.0f / 512.0f));
    float a = pos * inv;
    pe[(size_t)p * DM + f]       = (_Float16)sinf(a);
    pe[(size_t)p * DM + 512 + f] = (_Float16)cosf(a);
  }
}

// ---------------- cast ALL layers' weights fp32 -> f16, nontemporal ----------------
// Streamed-once data: nt loads/stores bypass L2/L3 (no cache thrash).
// Confirmed: 115 -> 84 us (3.9 TB/s) vs cached version.
__global__ __launch_bounds__(256) void cast_all_kernel(
    const float* __restrict__ qkv, const float* __restrict__ rw,
    const float* __restrict__ ow, const float* __restrict__ f1,
    const float* __restrict__ f2,
    _Float16* __restrict__ dq, _Float16* __restrict__ dr,
    _Float16* __restrict__ dow, _Float16* __restrict__ d1,
    _Float16* __restrict__ d2) {
  size_t i = (size_t)blockIdx.x * 4096;
  const float* s; _Float16* d; size_t off;
  if (i < 18874368)      { s = qkv; d = dq;  off = 0; }
  else if (i < 25165824) { s = rw;  d = dr;  off = 18874368; }
  else if (i < 31457280) { s = ow;  d = dow; off = 25165824; }
  else if (i < 56623104) { s = f1;  d = d1;  off = 31457280; }
  else                   { s = f2;  d = d2;  off = 56623104; }
  size_t kb = i - off + threadIdx.x * 8;
#pragma unroll
  for (int e = 0; e < 2; ++e) {
    size_t k = kb + e * 2048;
    f32x4 a = __builtin_nontemporal_load((const f32x4*)(s + k));
    f32x4 b = __builtin_nontemporal_load((const f32x4*)(s + k + 4));
    f16x8 o = { (_Float16)a.x, (_Float16)a.y, (_Float16)a.z, (_Float16)a.w,
                (_Float16)b.x, (_Float16)b.y, (_Float16)b.z, (_Float16)b.w };
    __builtin_nontemporal_store(o, (f16x8*)(d + k));
  }
}

// ---------------- LayerNorm over D=1024; optional 2-source concat ----------------
template <int OUTF16>
__global__ __launch_bounds__(256) void ln_kernel(
    const float* __restrict__ src0, const float* __restrict__ src1,
    const float* __restrict__ g, const float* __restrict__ b,
    float* __restrict__ outf, _Float16* __restrict__ outh, int rows0) {
  __shared__ float sm4[4];
  int row = blockIdx.x;
  const float* src = (row < rows0) ? (src0 + (size_t)row * DM)
                                   : (src1 + (size_t)(row - rows0) * DM);
  float4 v = ((const float4*)src)[threadIdx.x];
  float mean = block_sum(v.x + v.y + v.z + v.w, sm4) * (1.0f / DM);
  float dx = v.x - mean, dy = v.y - mean, dz = v.z - mean, dw = v.w - mean;
  float var = block_sum(dx * dx + dy * dy + dz * dz + dw * dw, sm4) * (1.0f / DM);
  float rstd = rsqrtf(var + EPS);
  float4 gg = ((const float4*)g)[threadIdx.x];
  float4 bb = ((const float4*)b)[threadIdx.x];
  float ox = dx * rstd * gg.x + bb.x;
  float oy = dy * rstd * gg.y + bb.y;
  float oz = dz * rstd * gg.z + bb.z;
  float ow = dw * rstd * gg.w + bb.w;
  if (OUTF16) {
    f16x4 o = { (_Float16)ox, (_Float16)oy, (_Float16)oz, (_Float16)ow };
    *(f16x4*)(outh + (size_t)row * DM + threadIdx.x * 4) = o;
  } else {
    float4 o = { ox, oy, oz, ow };
    ((float4*)(outf + (size_t)row * DM))[threadIdx.x] = o;
  }
}

// ------- fused split-K reduce + residual (+bias) + LayerNorm, one block/row -------
template <int SK, int BIAS, int OUTF16>
__global__ __launch_bounds__(256) void reduce_ln_kernel(
    const _Float16* __restrict__ pk, const float* __restrict__ bias,
    const float* __restrict__ resid, const float* __restrict__ g,
    const float* __restrict__ b, float* __restrict__ xout,
    _Float16* __restrict__ houth, float* __restrict__ houtf, int MN) {
  __shared__ float sm4[4];
  const int row = blockIdx.x;
  const int c = threadIdx.x * 4;
  const size_t base = (size_t)row * DM + c;
  float s[4] = {};
#pragma unroll
  for (int z = 0; z < SK; ++z) {
    f16x4 v = *(const f16x4*)(pk + (size_t)z * MN + base);
#pragma unroll
    for (int e = 0; e < 4; ++e) s[e] += (float)v[e];
  }
  if (BIAS) {
    float4 bv = *(const float4*)(bias + c);
    s[0] += bv.x; s[1] += bv.y; s[2] += bv.z; s[3] += bv.w;
  }
  float4 rv = *(const float4*)(resid + base);
  s[0] += rv.x; s[1] += rv.y; s[2] += rv.z; s[3] += rv.w;
  float4 xo = { s[0], s[1], s[2], s[3] };
  *(float4*)(xout + base) = xo;
  float mean = block_sum(s[0] + s[1] + s[2] + s[3], sm4) * (1.0f / DM);
  float d0 = s[0] - mean, d1 = s[1] - mean, d2 = s[2] - mean, d3 = s[3] - mean;
  float var = block_sum(d0 * d0 + d1 * d1 + d2 * d2 + d3 * d3, sm4) * (1.0f / DM);
  float rstd = rsqrtf(var + EPS);
  float4 gg = *(const float4*)(g + c);
  float4 bb = *(const float4*)(b + c);
  float o0 = d0 * rstd * gg.x + bb.x, o1 = d1 * rstd * gg.y + bb.y;
  float o2 = d2 * rstd * gg.z + bb.z, o3 = d3 * rstd * gg.w + bb.w;
  if (OUTF16) {
    f16x4 oh = { (_Float16)o0, (_Float16)o1, (_Float16)o2, (_Float16)o3 };
    *(f16x4*)(houth + base) = oh;
  } else {
    float4 of = { o0, o1, o2, o3 };
    *(float4*)(houtf + base) = of;
  }
}

// ---------------- f16 MFMA GEMM, BK=64, XOR-swizzled LDS ----------------
template <int BIAS, int RELU, int RESID, int OUTF16>
__global__ __launch_bounds__(256) void gemm_mfma(
    const _Float16* __restrict__ A, const _Float16* __restrict__ B,
    const float* __restrict__ bias, const float* __restrict__ resid,
    float* __restrict__ Cf, _Float16* __restrict__ Ch,
    int M, int N, int K) {
  __shared__ alignas(16) _Float16 As[128 * 64];
  __shared__ alignas(16) _Float16 Bs[128 * 64];
  const int t = threadIdx.x;
  const int lane = t & 63, wid = t >> 6;
  const int li = lane & 15, g = lane >> 4;
  const int m0 = blockIdx.y * 128, n0 = blockIdx.x * 128;
  const int wm = (wid >> 1) * 64, wn = (wid & 1) * 64;

  const _Float16* Ap[4];
  const _Float16* Bp[4];
  _Float16 *Asw[4], *Bsw[4];
#pragma unroll
  for (int it = 0; it < 4; ++it) {
    int c = it * 256 + wid * 64 + lane;
    int rr = c >> 3, gk = ((c & 7) ^ (rr & 7)) * 8;
    Ap[it] = A + (size_t)(m0 + rr) * K + gk;
    Bp[it] = B + (size_t)(n0 + rr) * K + gk;
    Asw[it] = &As[(it * 256 + wid * 64) * 8];
    Bsw[it] = &Bs[(it * 256 + wid * 64) * 8];
  }

  f32x4 acc[4][4] = {};
  for (int k0 = 0; k0 < K; k0 += 64) {
    __syncthreads();
#pragma unroll
    for (int it = 0; it < 4; ++it) gload16(Ap[it] + k0, Asw[it]);
#pragma unroll
    for (int it = 0; it < 4; ++it) gload16(Bp[it] + k0, Bsw[it]);
    __syncthreads();
#pragma unroll
    for (int kh = 0; kh < 2; ++kh) {
      f16x8 af[4], bf[4];
      const int sl = ((kh * 4 + g) ^ (li & 7)) * 8;
#pragma unroll
      for (int f = 0; f < 4; ++f) {
        af[f] = *(const f16x8*)&As[(wm + f * 16 + li) * 64 + sl];
        bf[f] = *(const f16x8*)&Bs[(wn + f * 16 + li) * 64 + sl];
      }
#pragma unroll
      for (int i = 0; i < 4; ++i)
#pragma unroll
        for (int j = 0; j < 4; ++j)
          acc[i][j] = __builtin_amdgcn_mfma_f32_16x16x32_f16(af[i], bf[j], acc[i][j], 0, 0, 0);
    }
  }
#pragma unroll
  for (int i = 0; i < 4; ++i) {
#pragma unroll
    for (int j = 0; j < 4; ++j) {
      const int n = n0 + wn + j * 16 + li;
      float bv = 0.0f;
      if (BIAS) bv = bias[n];
#pragma unroll
      for (int r = 0; r < 4; ++r) {
        const int m = m0 + wm + i * 16 + g * 4 + r;
        float v = acc[i][j][r] + bv;
        if (RELU) v = fmaxf(v, 0.0f);
        if (RESID) v += resid[(size_t)m * N + n];
        if (OUTF16) Ch[(size_t)m * N + n] = (_Float16)v;
        else        Cf[(size_t)m * N + n] = v;
      }
    }
  }
}

// ---------------- split-K GEMM, BK=64, XOR-swizzled (Ks multiple of 64) ----------------
__global__ __launch_bounds__(256) void gemm_sk(
    const _Float16* __restrict__ A, const _Float16* __restrict__ B,
    _Float16* __restrict__ pk, int M, int N, int K, int Ks) {
  __shared__ alignas(16) _Float16 As[128 * 64];
  __shared__ alignas(16) _Float16 Bs[128 * 64];
  const int t = threadIdx.x;
  const int lane = t & 63, wid = t >> 6;
  const int li = lane & 15, g = lane >> 4;
  const int m0 = blockIdx.y * 128, n0 = blockIdx.x * 128;
  const int z = blockIdx.z;
  const int kbase = z * Ks;
  const int wm = (wid >> 1) * 64, wn = (wid & 1) * 64;

  const _Float16* Ap[4];
  const _Float16* Bp[4];
  _Float16 *Asw[4], *Bsw[4];
#pragma unroll
  for (int it = 0; it < 4; ++it) {
    int c = it * 256 + wid * 64 + lane;
    int rr = c >> 3, gk = ((c & 7) ^ (rr & 7)) * 8;
    Ap[it] = A + (size_t)(m0 + rr) * K + kbase + gk;
    Bp[it] = B + (size_t)(n0 + rr) * K + kbase + gk;
    Asw[it] = &As[(it * 256 + wid * 64) * 8];
    Bsw[it] = &Bs[(it * 256 + wid * 64) * 8];
  }

  f32x4 acc[4][4] = {};
  for (int k0 = 0; k0 < Ks; k0 += 64) {
    __syncthreads();
#pragma unroll
    for (int it = 0; it < 4; ++it) gload16(Ap[it] + k0, Asw[it]);
#pragma unroll
    for (int it = 0; it < 4; ++it) gload16(Bp[it] + k0, Bsw[it]);
    __syncthreads();
#pragma unroll
    for (int kh = 0; kh < 2; ++kh) {
      f16x8 af[4], bf[4];
      const int sl = ((kh * 4 + g) ^ (li & 7)) * 8;
#pragma unroll
      for (int f = 0; f < 4; ++f) {
        af[f] = *(const f16x8*)&As[(wm + f * 16 + li) * 64 + sl];
        bf[f] = *(const f16x8*)&Bs[(wn + f * 16 + li) * 64 + sl];
      }
#pragma unroll
      for (int i = 0; i < 4; ++i)
#pragma unroll
        for (int j = 0; j < 4; ++j)
          acc[i][j] = __builtin_amdgcn_mfma_f32_16x16x32_f16(af[i], bf[j], acc[i][j], 0, 0, 0);
    }
  }
  _Float16* out = pk + (size_t)z * M * N;
#pragma unroll
  for (int i = 0; i < 4; ++i)
#pragma unroll
    for (int j = 0; j < 4; ++j) {
      const int n = n0 + wn + j * 16 + li;
#pragma unroll
      for (int r = 0; r < 4; ++r) {
        const int m = m0 + wm + i * 16 + g * 4 + r;
        out[(size_t)m * N + n] = (_Float16)acc[i][j][r];
      }
    }
}

// ---------------- split-K reduce (no LN): C = sum_z pk[z] ----------------
template <int SK, int OUTF16>
__global__ __launch_bounds__(256) void reduce_k(
    const _Float16* __restrict__ pk, float* __restrict__ Cf,
    _Float16* __restrict__ Ch, int MN) {
  const int idx = (blockIdx.x * 256 + threadIdx.x) * 8;
  float s[8] = {};
#pragma unroll
  for (int zz = 0; zz < SK; ++zz) {
    f16x8 v = *(const f16x8*)(pk + (size_t)zz * MN + idx);
#pragma unroll
    for (int e = 0; e < 8; ++e) s[e] += (float)v[e];
  }
  if (OUTF16) {
    f16x8 o;
#pragma unroll
    for (int e = 0; e < 8; ++e) o[e] = (_Float16)s[e];
    *(f16x8*)(Ch + idx) = o;
  } else {
    float4 o0 = { s[0], s[1], s[2], s[3] };
    float4 o1 = { s[4], s[5], s[6], s[7] };
    *(float4*)(Cf + idx) = o0;
    *(float4*)(Cf + idx + 4) = o1;
  }
}

// ---------------- MFMA flash relative attention, KV-split x4 ----------------
// grid (8 q-tiles, 16 heads, 16 = batch + 4*z); 256 threads = 4 waves x 16 q-rows.
__global__ __launch_bounds__(256, 3) void attn_kernel(
    const _Float16* __restrict__ wh,  // (KL*B_, 3072) f16 qkv projections
    const _Float16* __restrict__ rk,  // rk_all + l*1024, row stride 6144
    const float* __restrict__ rwb,    // (16,64)
    const float* __restrict__ rrb,    // (16,64)
    _Float16* __restrict__ po,        // [4][QLEN*B_*1024] partial O-hat
    float* __restrict__ pm,           // [4][32768] running max (log2 domain)
    float* __restrict__ pl) {         // [4][32768] running sum
  __shared__ alignas(16) _Float16 KS[64 * 72];   // K tile
  __shared__ alignas(16) _Float16 VT[64 * 72];   // V^T tile [d][j]
  __shared__ alignas(16) _Float16 RR[128 * 72];  // R tile
  __shared__ alignas(16) _Float16 QS[4][16 * 72];  // per-wave: shifted QR, then P

  const int i0 = blockIdx.x * 64, n = blockIdx.y;
  const int b = blockIdx.z & 3, zz = blockIdx.z >> 2;
  const int t = threadIdx.x, lane = t & 63, wid = t >> 6;
  const int g = lane >> 4, li = lane & 15;
  const int strip = wid * 16;
  _Float16* QSw = QS[wid];

  f16x8 qw[2], qr[2];
#pragma unroll
  for (int ks_ = 0; ks_ < 2; ++ks_) {
    const _Float16* qp =
        wh + ((size_t)(MLEN + i0 + strip + li) * B_ + b) * 3072 + n * 64 + ks_ * 32 + g * 8;
    f16x8 qv = *(const f16x8*)qp;
#pragma unroll
    for (int e = 0; e < 8; ++e) {
      float f0 = (float)qv[e];
      qw[ks_][e] = (_Float16)(f0 + rwb[n * 64 + ks_ * 32 + g * 8 + e]);
      qr[ks_][e] = (_Float16)(f0 + rrb[n * 64 + ks_ * 32 + g * 8 + e]);
    }
  }

  f32x4 o_[4] = {};
  float mrun[4], lrun[4];
#pragma unroll
  for (int r = 0; r < 4; ++r) { mrun[r] = -INFINITY; lrun[r] = 0.0f; }

  const float SC = 0.125f * 1.44269504f;  // scale * log2(e): softmax in base 2
  const int ntiles = i0 / 64 + 3;
  for (int tt = zz; tt < ntiles; tt += 4) {
    const int j0 = tt * 64;
    __syncthreads();  // prev-tile reads of KS/VT/RR done
    {
      int row = t >> 2, c = (t & 3) * 16;
      const _Float16* kp = wh + ((size_t)(j0 + row) * B_ + b) * 3072 + 1024 + n * 64 + c;
      *(f16x8*)&KS[row * 72 + c] = *(const f16x8*)kp;
      *(f16x8*)&KS[row * 72 + c + 8] = *(const f16x8*)(kp + 8);
    }
#pragma unroll
    for (int it = 0; it < 2; ++it) {
      int j = t & 63, d0 = (t >> 6) * 8 + it * 32;
      f16x8 vv = *(const f16x8*)(wh + ((size_t)(j0 + j) * B_ + b) * 3072 + 2048 + n * 64 + d0);
#pragma unroll
      for (int e = 0; e < 8; ++e) VT[(d0 + e) * 72 + j] = vv[e];
    }
    {
      int row = t >> 1, c = (t & 1) * 32;
      int mrow = j0 - i0 + 448 + row;
      if (mrow > KL - 1) mrow = KL - 1;
      const _Float16* rp = rk + (size_t)mrow * 6144 + n * 64 + c;
#pragma unroll
      for (int cc = 0; cc < 32; cc += 8)
        *(f16x8*)&RR[row * 72 + c + cc] = *(const f16x8*)(rp + cc);
    }
    __syncthreads();
    // ---- QK^T: 4 col-frags ----
    f32x4 acs[4] = {};
#pragma unroll
    for (int ks_ = 0; ks_ < 2; ++ks_)
#pragma unroll
      for (int cf = 0; cf < 4; ++cf) {
        f16x8 bk = *(const f16x8*)&KS[(cf * 16 + li) * 72 + ks_ * 32 + g * 8];
        acs[cf] = __builtin_amdgcn_mfma_f32_16x16x32_f16(qw[ks_], bk, acs[cf], 0, 0, 0);
      }
    // ---- QR; shifted store QSw[il_loc][jl] = QR[il][jl-il+63] (wave-private) ----
#pragma unroll
    for (int half = 0; half < 2; ++half) {
      f32x4 acq[4] = {};
#pragma unroll
      for (int ks_ = 0; ks_ < 2; ++ks_)
#pragma unroll
        for (int cf = 0; cf < 4; ++cf) {
          f16x8 br = *(const f16x8*)&RR[((half * 4 + cf) * 16 + li) * 72 + ks_ * 32 + g * 8];
          acq[cf] = __builtin_amdgcn_mfma_f32_16x16x32_f16(qr[ks_], br, acq[cf], 0, 0, 0);
        }
#pragma unroll
      for (int cf = 0; cf < 4; ++cf)
#pragma unroll
        for (int r = 0; r < 4; ++r) {
          int il = strip + g * 4 + r;
          int jl = (half * 4 + cf) * 16 + li - 63 + il;
          if ((unsigned)jl < 64u) QSw[(g * 4 + r) * 72 + jl] = (_Float16)acq[cf][r];
        }
    }
    // ---- online softmax (log2 domain) — wave-private, no barrier ----
    float pf[4][4], fac[4];
#pragma unroll
    for (int r = 0; r < 4; ++r) {
      int il = strip + g * 4 + r, gi = i0 + il;
      float sv[4], mx = -INFINITY;
#pragma unroll
      for (int cf = 0; cf < 4; ++cf) {
        int jl = cf * 16 + li;
        float v = (acs[cf][r] + (float)QSw[(g * 4 + r) * 72 + jl]) * SC;
        if (j0 + jl > gi + MLEN) v = -INFINITY;
        sv[cf] = v;
        mx = fmaxf(mx, v);
      }
#pragma unroll
      for (int o2 = 1; o2 < 16; o2 <<= 1) mx = fmaxf(mx, __shfl_xor(mx, o2, 64));
      float mnew = fmaxf(mrun[r], mx);
      float fc = exp2f(mrun[r] - mnew);
      float sum = 0.0f;
#pragma unroll
      for (int cf = 0; cf < 4; ++cf) { pf[cf][r] = exp2f(sv[cf] - mnew); sum += pf[cf][r]; }
#pragma unroll
      for (int o2 = 1; o2 < 16; o2 <<= 1) sum += __shfl_xor(sum, o2, 64);
      lrun[r] = lrun[r] * fc + sum;
      mrun[r] = mnew;
      fac[r] = fc;
    }
    // ---- P -> QSw (wave-private overwrite, in-order DS) ----
#pragma unroll
    for (int cf = 0; cf < 4; ++cf)
#pragma unroll
      for (int r = 0; r < 4; ++r)
        QSw[(g * 4 + r) * 72 + cf * 16 + li] = (_Float16)pf[cf][r];
    // ---- PV: O = O*fac + P V ----
#pragma unroll
    for (int cf = 0; cf < 4; ++cf)
#pragma unroll
      for (int r = 0; r < 4; ++r)
        o_[cf][r] *= fac[r];
#pragma unroll
    for (int ks_ = 0; ks_ < 2; ++ks_) {
      f16x8 pa = *(const f16x8*)&QSw[li * 72 + ks_ * 32 + g * 8];
#pragma unroll
      for (int cf = 0; cf < 4; ++cf) {
        f16x8 bv = *(const f16x8*)&VT[(cf * 16 + li) * 72 + ks_ * 32 + g * 8];
        o_[cf] = __builtin_amdgcn_mfma_f32_16x16x32_f16(pa, bv, o_[cf], 0, 0, 0);
      }
    }
  }
  const size_t obase = (size_t)zz * (QLEN * B_ * 1024);
#pragma unroll
  for (int cf = 0; cf < 4; ++cf)
#pragma unroll
    for (int r = 0; r < 4; ++r) {
      int row = strip + g * 4 + r;
      float l = lrun[r];
      float oo = (l > 0.0f) ? o_[cf][r] / l : 0.0f;
      po[obase + ((size_t)(i0 + row) * B_ + b) * 1024 + n * 64 + cf * 16 + li] = (_Float16)oo;
    }
  if (li == 0) {
#pragma unroll
    for (int r = 0; r < 4; ++r) {
      int row = strip + g * 4 + r;
      int idx = ((i0 + row) * B_ + b) * 16 + n;
      pm[zz * 32768 + idx] = (lrun[r] > 0.0f) ? mrun[r] : -3.0e38f;
      pl[zz * 32768 + idx] = lrun[r];
    }
  }
}

// ---------------- combine the four KV-split slices ----------------
__global__ __launch_bounds__(256) void attn_combine(
    const _Float16* __restrict__ po, const float* __restrict__ pm,
    const float* __restrict__ pl, _Float16* __restrict__ av) {
  const size_t e = ((size_t)blockIdx.x * 256 + threadIdx.x) * 8;
  const int mlidx = (int)(e >> 10) * 16 + (((int)e & 1023) >> 6);
  float m[4], l[4];
#pragma unroll
  for (int z = 0; z < 4; ++z) { m[z] = pm[z * 32768 + mlidx]; l[z] = pl[z * 32768 + mlidx]; }
  float M = fmaxf(fmaxf(m[0], m[1]), fmaxf(m[2], m[3]));
  float w[4], wsum = 0.0f;
#pragma unroll
  for (int z = 0; z < 4; ++z) { w[z] = l[z] * exp2f(m[z] - M); wsum += w[z]; }
  float inv = 1.0f / wsum;
  float s[8] = {};
#pragma unroll
  for (int z = 0; z < 4; ++z) {
    f16x8 oz = *(const f16x8*)(po + (size_t)z * 2097152 + e);
    float wz = w[z] * inv;
#pragma unroll
    for (int k = 0; k < 8; ++k) s[k] += wz * (float)oz[k];
  }
  f16x8 o;
#pragma unroll
  for (int k = 0; k < 8; ++k) o[k] = (_Float16)s[k];
  *(f16x8*)(av + e) = o;
}

// ---------------- host ----------------
extern "C" void kernel_launch(void* const* d_in, const int* in_sizes, int n_in,
                              void* d_out, int out_size, void* d_ws, size_t ws_size,
                              hipStream_t stream) {
  const float* inputs = (const float*)d_in[0];
  const float* mems   = (const float*)d_in[1];
  const float* rwb    = (const float*)d_in[2];
  const float* rrb    = (const float*)d_in[3];
  const float* qkv_w  = (const float*)d_in[4];
  const float* r_w    = (const float*)d_in[5];
  const float* o_w    = (const float*)d_in[6];
  const float* ln1_g  = (const float*)d_in[7];
  const float* ln1_b  = (const float*)d_in[8];
  const float* ff_w1  = (const float*)d_in[9];
  const float* ff_b1  = (const float*)d_in[10];
  const float* ff_w2  = (const float*)d_in[11];
  const float* ff_b2  = (const float*)d_in[12];
  const float* ln2_g  = (const float*)d_in[13];
  const float* ln2_b  = (const float*)d_in[14];
  const float* fin_g  = (const float*)d_in[15];
  const float* fin_b  = (const float*)d_in[16];
  float* out = (float*)d_out;

  float* ws = (float*)d_ws;
  float* xbuf = ws;                               // 2,097,152 f32 (8MB)
  _Float16* fb = (_Float16*)(ws + 2097152);
  _Float16* wh_h   = fb;                          //  7,864,320
  _Float16* rk_all = wh_h + 7864320;              //  3,932,160 (640 x 6144, all layers)
  _Float16* pe_h   = rk_all + 3932160;            //    655,360
  _Float16* h_h    = pe_h + 655360;               //  2,621,440
  _Float16* av_h   = h_h + 2621440;               //  2,097,152
  _Float16* ffh_h  = av_h + 2097152;              //  8,388,608
  _Float16* pk     = ffh_h + 8388608;             //  8,388,608 (split-K partials)
  _Float16* po     = pk + 8388608;                //  8,388,608 (attn partial O x4)
  float*    pm     = (float*)(po + 8388608);      //  131,072 f32
  float*    pl     = pm + 131072;                 //  131,072 f32
  _Float16* wq_all = (_Float16*)(pl + 131072);    // 18,874,368
  _Float16* rw_all = wq_all + 18874368;           //  6,291,456
  _Float16* wo_all = rw_all + 6291456;            //  6,291,456
  _Float16* w1_all = wo_all + 6291456;            // 25,165,824
  _Float16* w2_all = w1_all + 25165824;           // 25,165,824  (total ~273MB < 384MB ws)

  // ---- upfront: pos emb, all-layer weight cast, all-layer r_head_k ----
  pos_emb_kernel<<<KL, 256, 0, stream>>>(pe_h);
  cast_all_kernel<<<19968, 256, 0, stream>>>(
      qkv_w, r_w, o_w, ff_w1, ff_w2, wq_all, rw_all, wo_all, w1_all, w2_all);
  gemm_sk<<<dim3(6144 / 128, 640 / 128, 2), 256, 0, stream>>>(
      pe_h, rw_all, pk, KL, 6144, DM, DM / 2);
  reduce_k<2, 1><<<KL * 6144 / 2048, 256, 0, stream>>>(
      pk, nullptr, rk_all, KL * 6144);

  // layer-0 LN1 over [mems_0 ; inputs] -> h_h (2560 rows)
  ln_kernel<1><<<KL * B_, 256, 0, stream>>>(
      mems, inputs, ln1_g, ln1_b, nullptr, h_h, MLEN * B_);

  const float* xcur = inputs;
  for (int l = 0; l < NL; ++l) {
    // QKV projection -> wh f16
    gemm_mfma<0, 0, 0, 1><<<dim3(3072 / 128, 2560 / 128), 256, 0, stream>>>(
        h_h, wq_all + (size_t)l * 3145728, nullptr, nullptr, nullptr, wh_h, 2560, 3072, DM);
    // attention (KV-split x4) -> partials -> combine -> av_h
    attn_kernel<<<dim3(QLEN / 64, NH, B_ * 4), 256, 0, stream>>>(
        wh_h, rk_all + (size_t)l * 1024, rwb, rrb, po, pm, pl);
    attn_combine<<<1024, 256, 0, stream>>>(po, pm, pl, av_h);
    // out projection: split-K=4 (Ks=256) -> fused reduce(+resid)+LN2 -> xbuf, h_h
    gemm_sk<<<dim3(DM / 128, (QLEN * B_) / 128, 4), 256, 0, stream>>>(
        av_h, wo_all + (size_t)l * 1048576, pk, QLEN * B_, DM, DM, DM / 4);
    reduce_ln_kernel<4, 0, 1><<<QLEN * B_, 256, 0, stream>>>(
        pk, nullptr, xcur, ln2_g + l * DM, ln2_b + l * DM, xbuf, h_h, nullptr,
        QLEN * B_ * DM);
    // FFN
    gemm_mfma<1, 1, 0, 1><<<dim3(DFF / 128, (QLEN * B_) / 128), 256, 0, stream>>>(
        h_h, w1_all + (size_t)l * 4194304, ff_b1 + (size_t)l * DFF, nullptr,
        nullptr, ffh_h, QLEN * B_, DFF, DM);
    gemm_sk<<<dim3(DM / 128, (QLEN * B_) / 128, 4), 256, 0, stream>>>(
        ffh_h, w2_all + (size_t)l * 4194304, pk, QLEN * B_, DM, DFF, DFF / 4);
    if (l < NL - 1) {
      reduce_ln_kernel<4, 1, 1><<<QLEN * B_, 256, 0, stream>>>(
          pk, ff_b2 + (size_t)l * DM, xbuf, ln1_g + (size_t)(l + 1) * DM,
          ln1_b + (size_t)(l + 1) * DM, xbuf, h_h + 524288, nullptr,
          QLEN * B_ * DM);
      ln_kernel<1><<<MLEN * B_, 256, 0, stream>>>(
          mems + (size_t)(l + 1) * MLEN * B_ * DM, nullptr,
          ln1_g + (size_t)(l + 1) * DM, ln1_b + (size_t)(l + 1) * DM,
          nullptr, h_h, 1 << 30);
    } else {
      reduce_ln_kernel<4, 1, 0><<<QLEN * B_, 256, 0, stream>>>(
          pk, ff_b2 + (size_t)l * DM, xbuf, fin_g, fin_b, xbuf, nullptr, out,
          QLEN * B_ * DM);
    }
    xcur = xbuf;
  }
}